// Round 1
// baseline (1067.741 us; speedup 1.0000x reference)
//
#include <hip/hip_runtime.h>
#include <cstdint>
#include <cstddef>

#define Bc 4
#define Lc 2048
#define Kc 30
#define Fc 416
#define Nc 128

// atom index map: N=0, C=1, Ca=2, Cb=3, O=4
__constant__ int c_pa[24] = {0,2,3,1,1,1,0,0,3,0,2,3,2,3,2,4,1,4,0,4,3,4,4,2};
__constant__ int c_pb[24] = {0,2,3,0,2,3,2,3,2,1,1,1,0,0,3,4,4,1,4,0,4,2,3,2};

__device__ __forceinline__ unsigned long long u64min(unsigned long long a, unsigned long long b) {
    return a < b ? a : b;
}

// ---------------- Kernel 1: top-k neighbors ----------------
__global__ __launch_bounds__(256) void topk_kernel(
    const float* __restrict__ X, const float* __restrict__ mask,
    int* __restrict__ eidx, float* __restrict__ dnb, float* __restrict__ outEidx)
{
#pragma clang fp contract(off)
    const int row = blockIdx.x;          // b*L + i
    const int b   = row >> 11;           // /2048
    const int i   = row & (Lc - 1);
    const int t   = threadIdx.x;
    const int lane = t & 63, wid = t >> 6;

    __shared__ float red_f[4];
    __shared__ unsigned long long red_k[4];
    __shared__ unsigned long long winner_s;

    const float* Xb = X + (size_t)(b * Lc) * 12;
    const float cix = Xb[(size_t)i * 12 + 3];
    const float ciy = Xb[(size_t)i * 12 + 4];
    const float ciz = Xb[(size_t)i * 12 + 5];
    const float mi = mask[row];

    float dloc[8], m2loc[8];
    float dmax = -1e30f;
    #pragma unroll
    for (int s = 0; s < 8; ++s) {
        const int j = t + s * 256;
        const float dx = Xb[(size_t)j * 12 + 3] - cix;
        const float dy = Xb[(size_t)j * 12 + 4] - ciy;
        const float dz = Xb[(size_t)j * 12 + 5] - ciz;
        const float ss = dx * dx + dy * dy + dz * dz;
        const float dist = sqrtf(ss + 1e-6f);
        const float m2 = mi * mask[b * Lc + j];
        const float D = m2 * dist;
        dloc[s] = D; m2loc[s] = m2;
        dmax = fmaxf(dmax, D);
    }
    // block max (D_max)
    #pragma unroll
    for (int off = 32; off; off >>= 1) dmax = fmaxf(dmax, __shfl_xor(dmax, off, 64));
    if (lane == 0) red_f[wid] = dmax;
    __syncthreads();
    const float Dmax = fmaxf(fmaxf(red_f[0], red_f[1]), fmaxf(red_f[2], red_f[3]));

    unsigned long long key[8];
    #pragma unroll
    for (int s = 0; s < 8; ++s) {
        const int j = t + s * 256;
        const float Dadj = dloc[s] + (1.0f - m2loc[s]) * Dmax;
        key[s] = ((unsigned long long)__float_as_uint(Dadj) << 32) | (unsigned)j;
    }

    for (int n = 0; n < Kc; ++n) {
        unsigned long long k = key[0];
        #pragma unroll
        for (int s = 1; s < 8; ++s) k = u64min(k, key[s]);
        #pragma unroll
        for (int off = 32; off; off >>= 1) {
            unsigned long long o = (unsigned long long)__shfl_xor((long long)k, off, 64);
            k = u64min(k, o);
        }
        if (lane == 0) red_k[wid] = k;
        __syncthreads();
        if (t == 0) {
            unsigned long long w = red_k[0];
            w = u64min(w, red_k[1]); w = u64min(w, red_k[2]); w = u64min(w, red_k[3]);
            winner_s = w;
            const int j = (int)(w & 0xffffffffULL);
            const float dv = __uint_as_float((unsigned)(w >> 32));
            eidx[row * Kc + n] = j;
            dnb[row * Kc + n] = dv;
            outEidx[(size_t)row * Kc + n] = (float)j;
        }
        __syncthreads();
        const unsigned long long w = winner_s;
        #pragma unroll
        for (int s = 0; s < 8; ++s) if (key[s] == w) key[s] = ~0ULL;
    }
}

// ---------------- Kernel 2: features + GEMM + LayerNorm ----------------
__global__ __launch_bounds__(256) void edge_kernel(
    const float* __restrict__ X, const int* __restrict__ ridx, const int* __restrict__ clab,
    const float* __restrict__ pe_w, const float* __restrict__ pe_b,
    const float* __restrict__ Wg, const float* __restrict__ ln_g, const float* __restrict__ ln_b,
    const int* __restrict__ eidx, const float* __restrict__ dnb,
    float* __restrict__ outE)
{
    __shared__ float featT[Fc][33];       // transposed features, padded
    __shared__ float Wc[32 * 128];        // W chunk
    __shared__ float nbA[Kc][5][3];       // neighbor atoms N,C,Ca,Cb,O
    __shared__ float aiA[5][3];           // atoms of residue i
    __shared__ int jn[Kc];

    const int row = blockIdx.x;
    const int b   = row >> 11;
    const int i   = row & (Lc - 1);
    const int t   = threadIdx.x;

    // --- load atoms, compute Cb ---
    if (t <= Kc) {
        const int j = (t < Kc) ? eidx[row * Kc + t] : i;
        const float* p = X + (size_t)(b * Lc + j) * 12;
        const float Nx = p[0],  Ny = p[1],  Nz = p[2];
        const float Cx = p[3],  Cy = p[4],  Cz = p[5];
        const float Cax = p[6], Cay = p[7], Caz = p[8];
        const float Ox = p[9],  Oy = p[10], Oz = p[11];
        const float bx = Cax - Nx, by = Cay - Ny, bz = Caz - Nz;
        const float cx = Cx - Cax, cy = Cy - Cay, cz = Cz - Caz;
        const float ax = by * cz - bz * cy;
        const float ay = bz * cx - bx * cz;
        const float az = bx * cy - by * cx;
        const float Cbx = -0.58273431f * ax + 0.56802827f * bx - 0.54067466f * cx + Cax;
        const float Cby = -0.58273431f * ay + 0.56802827f * by - 0.54067466f * cy + Cay;
        const float Cbz = -0.58273431f * az + 0.56802827f * bz - 0.54067466f * cz + Caz;
        float* dst = (t < Kc) ? &nbA[t][0][0] : &aiA[0][0];
        dst[0] = Nx;  dst[1] = Ny;  dst[2] = Nz;
        dst[3] = Cx;  dst[4] = Cy;  dst[5] = Cz;
        dst[6] = Cax; dst[7] = Cay; dst[8] = Caz;
        dst[9] = Cbx; dst[10] = Cby; dst[11] = Cbz;
        dst[12] = Ox; dst[13] = Oy; dst[14] = Oz;
        if (t < Kc) jn[t] = j;
    }
    __syncthreads();

    // --- features ---
    if (t < 240) {
        const int kk = t >> 3, q = t & 7;
        const float* Ai = &aiA[0][0];
        const float* Bj = &nbA[kk][0][0];
        for (int p = q; p < 24; p += 8) {
            const int a_ = c_pa[p], b_ = c_pb[p];
            const float dx = Ai[a_ * 3 + 0] - Bj[b_ * 3 + 0];
            const float dy = Ai[a_ * 3 + 1] - Bj[b_ * 3 + 1];
            const float dz = Ai[a_ * 3 + 2] - Bj[b_ * 3 + 2];
            const float d = sqrtf(dx * dx + dy * dy + dz * dz + 1e-6f);
            #pragma unroll
            for (int m = 0; m < 16; ++m) {
                const float mu = 2.0f + (4.0f / 3.0f) * m;
                const float u = (d - mu) * 0.8f;      // /1.25
                featT[32 + p * 16 + m][kk] = __expf(-u * u) == 0.0f ? expf(-u * u) : expf(-u * u);
            }
        }
        if (q == 0) {
            const float dn = dnb[row * Kc + kk];
            #pragma unroll
            for (int m = 0; m < 16; ++m) {
                const float mu = 2.0f + (4.0f / 3.0f) * m;
                const float u = (dn - mu) * 0.8f;
                featT[16 + m][kk] = expf(-u * u);
            }
            const int j = jn[kk];
            const int off = ridx[row] - ridx[b * Lc + j];
            const int ec = (clab[row] == clab[b * Lc + j]) ? 1 : 0;
            const int d_ = ec ? min(max(off + 32, 0), 64) : 65;
            #pragma unroll
            for (int m = 0; m < 16; ++m) {
                featT[m][kk] = pe_w[d_ * 16 + m] + pe_b[m];
            }
        }
    }

    // --- GEMM: E[30][128] = featT^T @ W ---
    const int rg = t >> 3;   // row (neighbor slot), 0..31
    const int cg = t & 7;    // 16-col group
    float acc[16];
    #pragma unroll
    for (int u = 0; u < 16; ++u) acc[u] = 0.0f;

    for (int kc = 0; kc < 13; ++kc) {
        __syncthreads();
        {
            float4* d4 = (float4*)Wc;
            const float4* s4 = (const float4*)(Wg + (size_t)(kc * 32) * 128);
            #pragma unroll
            for (int u = 0; u < 4; ++u) d4[t + u * 256] = s4[t + u * 256];
        }
        __syncthreads();
        #pragma unroll 4
        for (int kk = 0; kk < 32; ++kk) {
            const float f = featT[kc * 32 + kk][rg];
            const float* wrow = &Wc[kk * 128 + cg * 16];
            #pragma unroll
            for (int u2 = 0; u2 < 4; ++u2) {
                const float4 w4 = *(const float4*)(wrow + u2 * 4);
                acc[u2 * 4 + 0] += f * w4.x;
                acc[u2 * 4 + 1] += f * w4.y;
                acc[u2 * 4 + 2] += f * w4.z;
                acc[u2 * 4 + 3] += f * w4.w;
            }
        }
    }

    // --- LayerNorm + store ---
    if (rg < Kc) {
        float s1 = 0.0f, s2 = 0.0f;
        #pragma unroll
        for (int u = 0; u < 16; ++u) { s1 += acc[u]; s2 += acc[u] * acc[u]; }
        #pragma unroll
        for (int off = 1; off < 8; off <<= 1) {
            s1 += __shfl_xor(s1, off, 64);
            s2 += __shfl_xor(s2, off, 64);
        }
        const float mu = s1 * (1.0f / 128.0f);
        const float var = s2 * (1.0f / 128.0f) - mu * mu;
        const float rstd = rsqrtf(var + 1e-5f);
        const size_t base = ((size_t)row * Kc + rg) * 128 + cg * 16;
        #pragma unroll
        for (int u2 = 0; u2 < 4; ++u2) {
            float4 o;
            const int c0 = cg * 16 + u2 * 4;
            o.x = (acc[u2 * 4 + 0] - mu) * rstd * ln_g[c0 + 0] + ln_b[c0 + 0];
            o.y = (acc[u2 * 4 + 1] - mu) * rstd * ln_g[c0 + 1] + ln_b[c0 + 1];
            o.z = (acc[u2 * 4 + 2] - mu) * rstd * ln_g[c0 + 2] + ln_b[c0 + 2];
            o.w = (acc[u2 * 4 + 3] - mu) * rstd * ln_g[c0 + 3] + ln_b[c0 + 3];
            *(float4*)(outE + base + u2 * 4) = o;
        }
    }
}

extern "C" void kernel_launch(void* const* d_in, const int* in_sizes, int n_in,
                              void* d_out, int out_size, void* d_ws, size_t ws_size,
                              hipStream_t stream) {
    const float* X     = (const float*)d_in[0];
    const float* mask  = (const float*)d_in[1];
    const int*   ridx  = (const int*)d_in[2];
    const int*   clab  = (const int*)d_in[3];
    const float* pe_w  = (const float*)d_in[4];
    const float* pe_b  = (const float*)d_in[5];
    const float* edge_w = (const float*)d_in[6];
    const float* ln_g  = (const float*)d_in[7];
    const float* ln_b  = (const float*)d_in[8];

    float* outE   = (float*)d_out;
    float* outIdx = outE + (size_t)Bc * Lc * Kc * Nc;   // E_idx region (as float)

    int*   eidx = (int*)d_ws;
    float* dnbw = (float*)((char*)d_ws + (size_t)Bc * Lc * Kc * sizeof(int));

    topk_kernel<<<Bc * Lc, 256, 0, stream>>>(X, mask, eidx, dnbw, outIdx);
    edge_kernel<<<Bc * Lc, 256, 0, stream>>>(X, ridx, clab, pe_w, pe_b, edge_w,
                                             ln_g, ln_b, eidx, dnbw, outE);
}

// Round 2
// 257.763 us; speedup vs baseline: 4.1423x; 4.1423x over previous
//
#include <hip/hip_runtime.h>
#include <hip/hip_bf16.h>
#include <cstdint>
#include <cstddef>

#define Bc 4
#define Lc 2048
#define Kc 30
#define Fc 416
#define Nc 128

typedef __bf16 bf16x8 __attribute__((ext_vector_type(8)));
typedef float  f32x4  __attribute__((ext_vector_type(4)));
typedef unsigned short ushortx8 __attribute__((ext_vector_type(8)));

// atom index map: N=0, C=1, Ca=2, Cb=3, O=4
__constant__ int c_pa[24] = {0,2,3,1,1,1,0,0,3,0,2,3,2,3,2,4,1,4,0,4,3,4,4,2};
__constant__ int c_pb[24] = {0,2,3,0,2,3,2,3,2,1,1,1,0,0,3,4,4,1,4,0,4,2,3,2};

__device__ __forceinline__ unsigned long long u64min(unsigned long long a, unsigned long long b) {
    return a < b ? a : b;
}

__device__ __forceinline__ unsigned short f2bf(float f) {
    __hip_bfloat16 h = __float2bfloat16(f);
    return *(unsigned short*)&h;
}

// ---------------- Kernel 0: W -> bf16, transposed Wt[n][k] ----------------
__global__ __launch_bounds__(256) void prep_w(const float* __restrict__ Wg,
                                              unsigned short* __restrict__ Wt) {
    const int id = blockIdx.x * 256 + threadIdx.x;   // 416*128 = 53248
    if (id < Fc * Nc) {
        const int n = id / Fc, k = id - n * Fc;
        Wt[id] = f2bf(Wg[k * Nc + n]);
    }
}

// ---------------- Kernel 1: top-k neighbors ----------------
__global__ __launch_bounds__(256) void topk_kernel(
    const float* __restrict__ X, const float* __restrict__ mask,
    int* __restrict__ eidx, float* __restrict__ dnb, float* __restrict__ outEidx)
{
#pragma clang fp contract(off)
    const int row = blockIdx.x;          // b*L + i
    const int b   = row >> 11;
    const int i   = row & (Lc - 1);
    const int t   = threadIdx.x;
    const int lane = t & 63, wid = t >> 6;

    __shared__ float red_f[4];
    __shared__ unsigned long long red_k[4];
    __shared__ unsigned long long winner_s;

    const float* Xb = X + (size_t)(b * Lc) * 12;
    const float cix = Xb[(size_t)i * 12 + 3];
    const float ciy = Xb[(size_t)i * 12 + 4];
    const float ciz = Xb[(size_t)i * 12 + 5];
    const float mi = mask[row];

    float dloc[8], m2loc[8];
    float dmax = -1e30f;
    #pragma unroll
    for (int s = 0; s < 8; ++s) {
        const int j = t + s * 256;
        const float dx = Xb[(size_t)j * 12 + 3] - cix;
        const float dy = Xb[(size_t)j * 12 + 4] - ciy;
        const float dz = Xb[(size_t)j * 12 + 5] - ciz;
        const float ss = dx * dx + dy * dy + dz * dz;
        const float dist = sqrtf(ss + 1e-6f);
        const float m2 = mi * mask[b * Lc + j];
        const float D = m2 * dist;
        dloc[s] = D; m2loc[s] = m2;
        dmax = fmaxf(dmax, D);
    }
    #pragma unroll
    for (int off = 32; off; off >>= 1) dmax = fmaxf(dmax, __shfl_xor(dmax, off, 64));
    if (lane == 0) red_f[wid] = dmax;
    __syncthreads();
    const float Dmax = fmaxf(fmaxf(red_f[0], red_f[1]), fmaxf(red_f[2], red_f[3]));

    unsigned long long key[8];
    #pragma unroll
    for (int s = 0; s < 8; ++s) {
        const int j = t + s * 256;
        const float Dadj = dloc[s] + (1.0f - m2loc[s]) * Dmax;
        key[s] = ((unsigned long long)__float_as_uint(Dadj) << 32) | (unsigned)j;
    }

    for (int n = 0; n < Kc; ++n) {
        unsigned long long k = key[0];
        #pragma unroll
        for (int s = 1; s < 8; ++s) k = u64min(k, key[s]);
        #pragma unroll
        for (int off = 32; off; off >>= 1) {
            unsigned long long o = (unsigned long long)__shfl_xor((long long)k, off, 64);
            k = u64min(k, o);
        }
        if (lane == 0) red_k[wid] = k;
        __syncthreads();
        if (t == 0) {
            unsigned long long w = red_k[0];
            w = u64min(w, red_k[1]); w = u64min(w, red_k[2]); w = u64min(w, red_k[3]);
            winner_s = w;
            const int j = (int)(w & 0xffffffffULL);
            const float dv = __uint_as_float((unsigned)(w >> 32));
            eidx[row * Kc + n] = j;
            dnb[row * Kc + n] = dv;
            outEidx[(size_t)row * Kc + n] = (float)j;
        }
        __syncthreads();
        const unsigned long long w = winner_s;
        #pragma unroll
        for (int s = 0; s < 8; ++s) if (key[s] == w) key[s] = ~0ULL;
    }
}

// ---------------- Kernel 2: features + MFMA GEMM + LayerNorm ----------------
// block = 4 residues (120 edges, M padded to 128), N=128, K=416 chunked by 32
__global__ __launch_bounds__(256) void edge_mfma(
    const float* __restrict__ X, const int* __restrict__ ridx, const int* __restrict__ clab,
    const float* __restrict__ pe_w, const float* __restrict__ pe_b,
    const unsigned short* __restrict__ Wt,   // bf16 [128][416] (n-major)
    const float* __restrict__ ln_g, const float* __restrict__ ln_b,
    const int* __restrict__ eidx, const float* __restrict__ dnb,
    float* __restrict__ outE)
{
    __shared__ unsigned short A[128][40];    // feature chunk, bf16, row pad 40
    __shared__ unsigned short Bs[128][40];   // Wt chunk [n][k], bf16, row pad 40
    __shared__ float atomsA[4][16];          // residue atoms (N,C,Ca,Cb,O)*3
    __shared__ float atomsB[120][16];        // neighbor atoms
    __shared__ float dnb_s[120];
    __shared__ int   pidx[120];              // positional embedding row

    const int blk = blockIdx.x;              // 2048
    const int t   = threadIdx.x;
    const int lane = t & 63, w = t >> 6;
    const int b   = blk >> 9;                // batch (512 blocks per batch)

    // --- staging: atoms + Cb for 4 residues and their 120 neighbors ---
    if (t < 124) {
        int j, rowi = 0;
        float* dst;
        if (t < 120) {
            const int r = t / 30;
            rowi = blk * 4 + r;              // global residue row (b*L + i)
            j = eidx[rowi * Kc + (t - r * 30)];
            dst = &atomsB[t][0];
            dnb_s[t] = dnb[rowi * Kc + (t - r * 30)];
            const int off = ridx[rowi] - ridx[b * Lc + j];
            const int ec  = (clab[rowi] == clab[b * Lc + j]) ? 1 : 0;
            pidx[t] = ec ? min(max(off + 32, 0), 64) : 65;
        } else {
            j = (blk * 4 + (t - 120)) & (Lc - 1);
            dst = &atomsA[t - 120][0];
        }
        const float* p = X + (size_t)(b * Lc + j) * 12;
        const float Nx = p[0],  Ny = p[1],  Nz = p[2];
        const float Cx = p[3],  Cy = p[4],  Cz = p[5];
        const float Cax = p[6], Cay = p[7], Caz = p[8];
        const float Ox = p[9],  Oy = p[10], Oz = p[11];
        const float bx = Cax - Nx, by = Cay - Ny, bz = Caz - Nz;
        const float cx = Cx - Cax, cy = Cy - Cay, cz = Cz - Caz;
        const float ax = by * cz - bz * cy;
        const float ay = bz * cx - bx * cz;
        const float az = bx * cy - by * cx;
        dst[0] = Nx;  dst[1] = Ny;  dst[2] = Nz;
        dst[3] = Cx;  dst[4] = Cy;  dst[5] = Cz;
        dst[6] = Cax; dst[7] = Cay; dst[8] = Caz;
        dst[9]  = -0.58273431f * ax + 0.56802827f * bx - 0.54067466f * cx + Cax;
        dst[10] = -0.58273431f * ay + 0.56802827f * by - 0.54067466f * cy + Cay;
        dst[11] = -0.58273431f * az + 0.56802827f * bz - 0.54067466f * cz + Caz;
        dst[12] = Ox; dst[13] = Oy; dst[14] = Oz;
    }

    f32x4 acc[2][8];
    #pragma unroll
    for (int m = 0; m < 2; ++m)
        #pragma unroll
        for (int n = 0; n < 8; ++n) acc[m][n] = (f32x4){0.f, 0.f, 0.f, 0.f};

    const int kg = (lane >> 4) * 8;          // k-group offset within chunk
    const int cl = lane & 15;

    for (int kc = 0; kc < 13; ++kc) {
        __syncthreads();                     // staging done / prev MFMA reads done

        // load Wt chunk -> Bs (2x 16B per thread, coalesced 64B per n-row)
        {
            #pragma unroll
            for (int u = 0; u < 2; ++u) {
                const int id = u * 256 + t;  // 0..511
                const int n = id >> 2, g = id & 3;
                *(ushortx8*)&Bs[n][g * 8] =
                    *(const ushortx8*)&Wt[n * Fc + kc * 32 + g * 8];
            }
        }

        // compute feature chunk -> A
        if (t < 240) {
            const int e = t >> 1, h = t & 1;
            unsigned short v[16];
            if (kc == 0) {
                if (h == 0) {
                    const float* pr = pe_w + pidx[e] * 16;
                    #pragma unroll
                    for (int m = 0; m < 16; ++m) v[m] = f2bf(pr[m] + pe_b[m]);
                } else {
                    const float d = dnb_s[e];
                    #pragma unroll
                    for (int m = 0; m < 16; ++m) {
                        const float u = (d - (2.0f + (4.0f / 3.0f) * m)) * 0.8f;
                        v[m] = f2bf(expf(-u * u));
                    }
                }
            } else {
                const int p = 2 * kc - 2 + h;
                const int a_ = c_pa[p], b_ = c_pb[p];
                const float* Ai = &atomsA[e / 30][0];
                const float* Bj = &atomsB[e][0];
                const float dx = Ai[a_ * 3 + 0] - Bj[b_ * 3 + 0];
                const float dy = Ai[a_ * 3 + 1] - Bj[b_ * 3 + 1];
                const float dz = Ai[a_ * 3 + 2] - Bj[b_ * 3 + 2];
                const float d = sqrtf(dx * dx + dy * dy + dz * dz + 1e-6f);
                #pragma unroll
                for (int m = 0; m < 16; ++m) {
                    const float u = (d - (2.0f + (4.0f / 3.0f) * m)) * 0.8f;
                    v[m] = f2bf(expf(-u * u));
                }
            }
            ushortx8 lo, hi;
            #pragma unroll
            for (int m = 0; m < 8; ++m) { lo[m] = v[m]; hi[m] = v[m + 8]; }
            *(ushortx8*)&A[e][h * 16]     = lo;
            *(ushortx8*)&A[e][h * 16 + 8] = hi;
        }

        __syncthreads();

        // MFMA: wave w owns rows w*32..w*32+31, all 128 cols
        bf16x8 af0 = __builtin_bit_cast(bf16x8, *(const ushortx8*)&A[w * 32 + cl][kg]);
        bf16x8 af1 = __builtin_bit_cast(bf16x8, *(const ushortx8*)&A[w * 32 + 16 + cl][kg]);
        #pragma unroll
        for (int n = 0; n < 8; ++n) {
            bf16x8 bf = __builtin_bit_cast(bf16x8, *(const ushortx8*)&Bs[n * 16 + cl][kg]);
            acc[0][n] = __builtin_amdgcn_mfma_f32_16x16x32_bf16(af0, bf, acc[0][n], 0, 0, 0);
            acc[1][n] = __builtin_amdgcn_mfma_f32_16x16x32_bf16(af1, bf, acc[1][n], 0, 0, 0);
        }
    }

    // --- LayerNorm + store ---
    float gcol[8], bcol[8];
    #pragma unroll
    for (int n = 0; n < 8; ++n) {
        gcol[n] = ln_g[n * 16 + cl];
        bcol[n] = ln_b[n * 16 + cl];
    }
    #pragma unroll
    for (int m = 0; m < 2; ++m) {
        #pragma unroll
        for (int reg = 0; reg < 4; ++reg) {
            const int rl = w * 32 + m * 16 + (lane >> 4) * 4 + reg;
            float s1 = 0.f, s2 = 0.f;
            #pragma unroll
            for (int n = 0; n < 8; ++n) {
                const float v = acc[m][n][reg];
                s1 += v; s2 += v * v;
            }
            #pragma unroll
            for (int off = 1; off < 16; off <<= 1) {
                s1 += __shfl_xor(s1, off, 64);
                s2 += __shfl_xor(s2, off, 64);
            }
            if (rl < 120) {
                const float mu = s1 * (1.0f / 128.0f);
                const float var = s2 * (1.0f / 128.0f) - mu * mu;
                const float rstd = rsqrtf(var + 1e-5f);
                const size_t base = ((size_t)(blk * 120 + rl)) * 128 + cl;
                #pragma unroll
                for (int n = 0; n < 8; ++n) {
                    outE[base + n * 16] =
                        (acc[m][n][reg] - mu) * rstd * gcol[n] + bcol[n];
                }
            }
        }
    }
}

extern "C" void kernel_launch(void* const* d_in, const int* in_sizes, int n_in,
                              void* d_out, int out_size, void* d_ws, size_t ws_size,
                              hipStream_t stream) {
    const float* X     = (const float*)d_in[0];
    const float* mask  = (const float*)d_in[1];
    const int*   ridx  = (const int*)d_in[2];
    const int*   clab  = (const int*)d_in[3];
    const float* pe_w  = (const float*)d_in[4];
    const float* pe_b  = (const float*)d_in[5];
    const float* edge_w = (const float*)d_in[6];
    const float* ln_g  = (const float*)d_in[7];
    const float* ln_b  = (const float*)d_in[8];

    float* outE   = (float*)d_out;
    float* outIdx = outE + (size_t)Bc * Lc * Kc * Nc;   // E_idx region (as float)

    int*   eidx = (int*)d_ws;
    float* dnbw = (float*)((char*)d_ws + (size_t)Bc * Lc * Kc * sizeof(int));
    unsigned short* Wt = (unsigned short*)((char*)d_ws + (size_t)2 * Bc * Lc * Kc * sizeof(int));

    prep_w<<<(Fc * Nc + 255) / 256, 256, 0, stream>>>(edge_w, Wt);
    topk_kernel<<<Bc * Lc, 256, 0, stream>>>(X, mask, eidx, dnbw, outIdx);
    edge_mfma<<<Bc * Lc / 4, 256, 0, stream>>>(X, ridx, clab, pe_w, pe_b, Wt,
                                               ln_g, ln_b, eidx, dnbw, outE);
}

// Round 3
// 213.156 us; speedup vs baseline: 5.0092x; 1.2093x over previous
//
#include <hip/hip_runtime.h>
#include <hip/hip_bf16.h>
#include <cstdint>
#include <cstddef>

#define Bc 4
#define Lc 2048
#define Kc 30
#define Fc 416
#define Nc 128

typedef __bf16 bf16x8 __attribute__((ext_vector_type(8)));
typedef float  f32x4  __attribute__((ext_vector_type(4)));
typedef unsigned short ushortx8 __attribute__((ext_vector_type(8)));

// atom index map: N=0, C=1, Ca=2, Cb=3, O=4
__constant__ int c_pa[24] = {0,2,3,1,1,1,0,0,3,0,2,3,2,3,2,4,1,4,0,4,3,4,4,2};
__constant__ int c_pb[24] = {0,2,3,0,2,3,2,3,2,1,1,1,0,0,3,4,4,1,4,0,4,2,3,2};

__device__ __forceinline__ unsigned long long u64min(unsigned long long a, unsigned long long b) {
    return a < b ? a : b;
}

__device__ __forceinline__ unsigned short f2bf(float f) {
    __hip_bfloat16 h = __float2bfloat16(f);
    return *(unsigned short*)&h;
}

// ---------------- Kernel 0: W -> bf16, transposed Wt[n][k] ----------------
__global__ __launch_bounds__(256) void prep_w(const float* __restrict__ Wg,
                                              unsigned short* __restrict__ Wt) {
    const int id = blockIdx.x * 256 + threadIdx.x;   // 416*128 = 53248
    if (id < Fc * Nc) {
        const int n = id / Fc, k = id - n * Fc;
        Wt[id] = f2bf(Wg[k * Nc + n]);
    }
}

// ---------------- Kernel 1: top-k, one wave per row ----------------
// 32 candidates/lane as u64 keys, 2-level loser tree (4 groups of 8),
// 30 rounds of barrier-free wave reduction.
__global__ __launch_bounds__(256) void topk_wave(
    const float* __restrict__ X, const float* __restrict__ mask,
    int* __restrict__ eidx, float* __restrict__ dnb, float* __restrict__ outEidx)
{
#pragma clang fp contract(off)
    const int t = threadIdx.x;
    const int lane = t & 63, wv = t >> 6;
    const int row = blockIdx.x * 4 + wv;       // b*L + i
    const int b   = row >> 11;
    const int i   = row & (Lc - 1);

    const float* Xb = X + (size_t)(b * Lc) * 12;
    const float cix = Xb[(size_t)i * 12 + 3];
    const float ciy = Xb[(size_t)i * 12 + 4];
    const float ciz = Xb[(size_t)i * 12 + 5];
    const float mi  = mask[row];

    float D[32], M2[32];
    float dmax = -1e30f;
    #pragma unroll
    for (int s = 0; s < 32; ++s) {
        const int j = s * 64 + lane;
        const float dx = Xb[(size_t)j * 12 + 3] - cix;
        const float dy = Xb[(size_t)j * 12 + 4] - ciy;
        const float dz = Xb[(size_t)j * 12 + 5] - ciz;
        const float ss = dx * dx + dy * dy + dz * dz;
        const float dist = sqrtf(ss + 1e-6f);
        const float m2 = mi * mask[b * Lc + j];
        D[s] = m2 * dist;
        M2[s] = m2;
        dmax = fmaxf(dmax, D[s]);
    }
    #pragma unroll
    for (int off = 32; off; off >>= 1) dmax = fmaxf(dmax, __shfl_xor(dmax, off, 64));

    unsigned long long key[32];
    #pragma unroll
    for (int s = 0; s < 32; ++s) {
        const float Dadj = D[s] + (1.0f - M2[s]) * dmax;
        key[s] = ((unsigned long long)__float_as_uint(Dadj) << 32)
               | (unsigned)(s * 64 + lane);
    }

    unsigned long long g[4];
    #pragma unroll
    for (int gi = 0; gi < 4; ++gi) {
        unsigned long long m = key[gi * 8];
        #pragma unroll
        for (int s = 1; s < 8; ++s) m = u64min(m, key[gi * 8 + s]);
        g[gi] = m;
    }

    unsigned long long won = ~0ULL;
    for (int n = 0; n < Kc; ++n) {
        unsigned long long w = u64min(u64min(g[0], g[1]), u64min(g[2], g[3]));
        #pragma unroll
        for (int off = 32; off; off >>= 1) {
            const unsigned long long o = (unsigned long long)__shfl_xor((long long)w, off, 64);
            w = u64min(w, o);
        }
        if (lane == n) won = w;
        // owning lane invalidates and rebuilds its group min
        #pragma unroll
        for (int gi = 0; gi < 4; ++gi) {
            if (g[gi] == w) {
                unsigned long long m = ~0ULL;
                #pragma unroll
                for (int s = 0; s < 8; ++s) {
                    if (key[gi * 8 + s] == w) key[gi * 8 + s] = ~0ULL;
                    m = u64min(m, key[gi * 8 + s]);
                }
                g[gi] = m;
            }
        }
    }

    if (lane < Kc) {
        const int j = (int)(won & 0xffffffffULL);
        const float dv = __uint_as_float((unsigned)(won >> 32));
        eidx[row * Kc + lane] = j;
        dnb[row * Kc + lane] = dv;
        outEidx[(size_t)row * Kc + lane] = (float)j;
    }
}

// ---------------- Kernel 2: features + MFMA GEMM + LayerNorm ----------------
// block = 4 residues (120 edges, M padded to 128), N=128, K=416 chunked by 32
__global__ __launch_bounds__(256) void edge_mfma(
    const float* __restrict__ X, const int* __restrict__ ridx, const int* __restrict__ clab,
    const float* __restrict__ pe_w, const float* __restrict__ pe_b,
    const unsigned short* __restrict__ Wt,   // bf16 [128][416] (n-major)
    const float* __restrict__ ln_g, const float* __restrict__ ln_b,
    const int* __restrict__ eidx, const float* __restrict__ dnb,
    float* __restrict__ outE)
{
    __shared__ unsigned short A[128][40];    // feature chunk, bf16, row pad 40
    __shared__ unsigned short Bs[128][40];   // Wt chunk [n][k], bf16, row pad 40
    __shared__ float atomsA[4][16];          // residue atoms (N,C,Ca,Cb,O)*3
    __shared__ float atomsB[120][16];        // neighbor atoms
    __shared__ float dnb_s[120];
    __shared__ int   pidx[120];              // positional embedding row

    const int blk = blockIdx.x;              // 2048
    const int t   = threadIdx.x;
    const int lane = t & 63, w = t >> 6;
    const int b   = blk >> 9;                // batch (512 blocks per batch)

    // --- staging: atoms + Cb for 4 residues and their 120 neighbors ---
    if (t < 124) {
        int j, rowi = 0;
        float* dst;
        if (t < 120) {
            const int r = t / 30;
            rowi = blk * 4 + r;              // global residue row (b*L + i)
            j = eidx[rowi * Kc + (t - r * 30)];
            dst = &atomsB[t][0];
            dnb_s[t] = dnb[rowi * Kc + (t - r * 30)];
            const int off = ridx[rowi] - ridx[b * Lc + j];
            const int ec  = (clab[rowi] == clab[b * Lc + j]) ? 1 : 0;
            pidx[t] = ec ? min(max(off + 32, 0), 64) : 65;
        } else {
            j = (blk * 4 + (t - 120)) & (Lc - 1);
            dst = &atomsA[t - 120][0];
        }
        const float* p = X + (size_t)(b * Lc + j) * 12;
        const float Nx = p[0],  Ny = p[1],  Nz = p[2];
        const float Cx = p[3],  Cy = p[4],  Cz = p[5];
        const float Cax = p[6], Cay = p[7], Caz = p[8];
        const float Ox = p[9],  Oy = p[10], Oz = p[11];
        const float bx = Cax - Nx, by = Cay - Ny, bz = Caz - Nz;
        const float cx = Cx - Cax, cy = Cy - Cay, cz = Cz - Caz;
        const float ax = by * cz - bz * cy;
        const float ay = bz * cx - bx * cz;
        const float az = bx * cy - by * cx;
        dst[0] = Nx;  dst[1] = Ny;  dst[2] = Nz;
        dst[3] = Cx;  dst[4] = Cy;  dst[5] = Cz;
        dst[6] = Cax; dst[7] = Cay; dst[8] = Caz;
        dst[9]  = -0.58273431f * ax + 0.56802827f * bx - 0.54067466f * cx + Cax;
        dst[10] = -0.58273431f * ay + 0.56802827f * by - 0.54067466f * cy + Cay;
        dst[11] = -0.58273431f * az + 0.56802827f * bz - 0.54067466f * cz + Caz;
        dst[12] = Ox; dst[13] = Oy; dst[14] = Oz;
    }

    f32x4 acc[2][8];
    #pragma unroll
    for (int m = 0; m < 2; ++m)
        #pragma unroll
        for (int n = 0; n < 8; ++n) acc[m][n] = (f32x4){0.f, 0.f, 0.f, 0.f};

    const int kg = (lane >> 4) * 8;          // k-group offset within chunk
    const int cl = lane & 15;

    for (int kc = 0; kc < 13; ++kc) {
        __syncthreads();                     // staging done / prev MFMA reads done

        // load Wt chunk -> Bs (2x 16B per thread, coalesced 64B per n-row)
        {
            #pragma unroll
            for (int u = 0; u < 2; ++u) {
                const int id = u * 256 + t;  // 0..511
                const int n = id >> 2, g = id & 3;
                *(ushortx8*)&Bs[n][g * 8] =
                    *(const ushortx8*)&Wt[n * Fc + kc * 32 + g * 8];
            }
        }

        // compute feature chunk -> A
        if (t < 240) {
            const int e = t >> 1, h = t & 1;
            unsigned short v[16];
            if (kc == 0) {
                if (h == 0) {
                    const float* pr = pe_w + pidx[e] * 16;
                    #pragma unroll
                    for (int m = 0; m < 16; ++m) v[m] = f2bf(pr[m] + pe_b[m]);
                } else {
                    const float d = dnb_s[e];
                    #pragma unroll
                    for (int m = 0; m < 16; ++m) {
                        const float u = (d - (2.0f + (4.0f / 3.0f) * m)) * 0.8f;
                        v[m] = f2bf(__expf(-u * u));
                    }
                }
            } else {
                const int p = 2 * kc - 2 + h;
                const int a_ = c_pa[p], b_ = c_pb[p];
                const float* Ai = &atomsA[e / 30][0];
                const float* Bj = &atomsB[e][0];
                const float dx = Ai[a_ * 3 + 0] - Bj[b_ * 3 + 0];
                const float dy = Ai[a_ * 3 + 1] - Bj[b_ * 3 + 1];
                const float dz = Ai[a_ * 3 + 2] - Bj[b_ * 3 + 2];
                const float d = sqrtf(dx * dx + dy * dy + dz * dz + 1e-6f);
                #pragma unroll
                for (int m = 0; m < 16; ++m) {
                    const float u = (d - (2.0f + (4.0f / 3.0f) * m)) * 0.8f;
                    v[m] = f2bf(__expf(-u * u));
                }
            }
            ushortx8 lo, hi;
            #pragma unroll
            for (int m = 0; m < 8; ++m) { lo[m] = v[m]; hi[m] = v[m + 8]; }
            *(ushortx8*)&A[e][h * 16]     = lo;
            *(ushortx8*)&A[e][h * 16 + 8] = hi;
        }

        __syncthreads();

        // MFMA: wave w owns rows w*32..w*32+31, all 128 cols
        bf16x8 af0 = __builtin_bit_cast(bf16x8, *(const ushortx8*)&A[w * 32 + cl][kg]);
        bf16x8 af1 = __builtin_bit_cast(bf16x8, *(const ushortx8*)&A[w * 32 + 16 + cl][kg]);
        #pragma unroll
        for (int n = 0; n < 8; ++n) {
            bf16x8 bf = __builtin_bit_cast(bf16x8, *(const ushortx8*)&Bs[n * 16 + cl][kg]);
            acc[0][n] = __builtin_amdgcn_mfma_f32_16x16x32_bf16(af0, bf, acc[0][n], 0, 0, 0);
            acc[1][n] = __builtin_amdgcn_mfma_f32_16x16x32_bf16(af1, bf, acc[1][n], 0, 0, 0);
        }
    }

    // --- LayerNorm + store ---
    float gcol[8], bcol[8];
    #pragma unroll
    for (int n = 0; n < 8; ++n) {
        gcol[n] = ln_g[n * 16 + cl];
        bcol[n] = ln_b[n * 16 + cl];
    }
    #pragma unroll
    for (int m = 0; m < 2; ++m) {
        #pragma unroll
        for (int reg = 0; reg < 4; ++reg) {
            const int rl = w * 32 + m * 16 + (lane >> 4) * 4 + reg;
            float s1 = 0.f, s2 = 0.f;
            #pragma unroll
            for (int n = 0; n < 8; ++n) {
                const float v = acc[m][n][reg];
                s1 += v; s2 += v * v;
            }
            #pragma unroll
            for (int off = 1; off < 16; off <<= 1) {
                s1 += __shfl_xor(s1, off, 64);
                s2 += __shfl_xor(s2, off, 64);
            }
            if (rl < 120) {
                const float mu = s1 * (1.0f / 128.0f);
                const float var = s2 * (1.0f / 128.0f) - mu * mu;
                const float rstd = rsqrtf(var + 1e-5f);
                const size_t base = ((size_t)(blk * 120 + rl)) * 128 + cl;
                #pragma unroll
                for (int n = 0; n < 8; ++n) {
                    outE[base + n * 16] =
                        (acc[m][n][reg] - mu) * rstd * gcol[n] + bcol[n];
                }
            }
        }
    }
}

extern "C" void kernel_launch(void* const* d_in, const int* in_sizes, int n_in,
                              void* d_out, int out_size, void* d_ws, size_t ws_size,
                              hipStream_t stream) {
    const float* X     = (const float*)d_in[0];
    const float* mask  = (const float*)d_in[1];
    const int*   ridx  = (const int*)d_in[2];
    const int*   clab  = (const int*)d_in[3];
    const float* pe_w  = (const float*)d_in[4];
    const float* pe_b  = (const float*)d_in[5];
    const float* edge_w = (const float*)d_in[6];
    const float* ln_g  = (const float*)d_in[7];
    const float* ln_b  = (const float*)d_in[8];

    float* outE   = (float*)d_out;
    float* outIdx = outE + (size_t)Bc * Lc * Kc * Nc;   // E_idx region (as float)

    int*   eidx = (int*)d_ws;
    float* dnbw = (float*)((char*)d_ws + (size_t)Bc * Lc * Kc * sizeof(int));
    unsigned short* Wt = (unsigned short*)((char*)d_ws + (size_t)2 * Bc * Lc * Kc * sizeof(int));

    prep_w<<<(Fc * Nc + 255) / 256, 256, 0, stream>>>(edge_w, Wt);
    topk_wave<<<Bc * Lc / 4, 256, 0, stream>>>(X, mask, eidx, dnbw, outIdx);
    edge_mfma<<<Bc * Lc / 4, 256, 0, stream>>>(X, ridx, clab, pe_w, pe_b, Wt,
                                               ln_g, ln_b, eidx, dnbw, outE);
}

// Round 4
// 143.678 us; speedup vs baseline: 7.4315x; 1.4836x over previous
//
#include <hip/hip_runtime.h>
#include <hip/hip_bf16.h>
#include <cstdint>
#include <cstddef>

#define Bc 4
#define Lc 2048
#define Kc 30
#define Fc 416
#define Nc 128

typedef __bf16 bf16x8 __attribute__((ext_vector_type(8)));
typedef float  f32x4  __attribute__((ext_vector_type(4)));
typedef unsigned short ushortx8 __attribute__((ext_vector_type(8)));

// atom index map: N=0, C=1, Ca=2, Cb=3, O=4
__constant__ int c_pa[24] = {0,2,3,1,1,1,0,0,3,0,2,3,2,3,2,4,1,4,0,4,3,4,4,2};
__constant__ int c_pb[24] = {0,2,3,0,2,3,2,3,2,1,1,1,0,0,3,4,4,1,4,0,4,2,3,2};

__device__ __forceinline__ unsigned long long u64min(unsigned long long a, unsigned long long b) {
    return a < b ? a : b;
}

__device__ __forceinline__ unsigned short f2bf(float f) {
    __hip_bfloat16 h = __float2bfloat16(f);
    return *(unsigned short*)&h;
}

// ---------------- Kernel 0: W -> bf16, transposed Wt[n][k] ----------------
__global__ __launch_bounds__(256) void prep_w(const float* __restrict__ Wg,
                                              unsigned short* __restrict__ Wt) {
    const int id = blockIdx.x * 256 + threadIdx.x;   // 416*128 = 53248
    if (id < Fc * Nc) {
        const int n = id / Fc, k = id - n * Fc;
        Wt[id] = f2bf(Wg[k * Nc + n]);
    }
}

// ---------------- Kernel 1: top-k, one wave per row, pool in LDS ----------------
// Candidates live in LDS (per-wave private region, no barriers). Registers hold
// only a 4-entry u64 group-argmin tree -> ~40 VGPR -> high occupancy.
__global__ __launch_bounds__(256) void topk_lds(
    const float* __restrict__ X, const float* __restrict__ mask,
    int* __restrict__ eidx, float* __restrict__ dnb, float* __restrict__ outEidx)
{
#pragma clang fp contract(off)
    __shared__ float sval[4][32][64];          // [wave][s][lane], 32 KB
    const int t = threadIdx.x;
    const int lane = t & 63, wv = t >> 6;
    const int row = blockIdx.x * 4 + wv;       // b*L + i
    const int b   = row >> 11;
    const int i   = row & (Lc - 1);

    const float* Xb = X + (size_t)(b * Lc) * 12;
    const float cix = Xb[(size_t)i * 12 + 3];
    const float ciy = Xb[(size_t)i * 12 + 4];
    const float ciz = Xb[(size_t)i * 12 + 5];
    const float mi  = mask[row];

    // pass 1: D -> LDS, wave max
    float dmax = -1e30f;
    #pragma unroll 8
    for (int s = 0; s < 32; ++s) {
        const int j = s * 64 + lane;
        const float dx = Xb[(size_t)j * 12 + 3] - cix;
        const float dy = Xb[(size_t)j * 12 + 4] - ciy;
        const float dz = Xb[(size_t)j * 12 + 5] - ciz;
        const float ss = dx * dx + dy * dy + dz * dz;
        const float dist = sqrtf(ss + 1e-6f);
        const float D = (mi * mask[b * Lc + j]) * dist;
        sval[wv][s][lane] = D;
        dmax = fmaxf(dmax, D);
    }
    #pragma unroll
    for (int off = 32; off; off >>= 1) dmax = fmaxf(dmax, __shfl_xor(dmax, off, 64));

    // pass 2: Dadj -> LDS, build group argmins (u64 = valbits<<32 | j)
    unsigned long long g[4] = {~0ULL, ~0ULL, ~0ULL, ~0ULL};
    #pragma unroll 8
    for (int s = 0; s < 32; ++s) {
        const int j = s * 64 + lane;
        const float m2 = mi * mask[b * Lc + j];
        const float Dadj = sval[wv][s][lane] + (1.0f - m2) * dmax;
        sval[wv][s][lane] = Dadj;
        const unsigned long long k =
            ((unsigned long long)__float_as_uint(Dadj) << 32) | (unsigned)j;
        g[s >> 3] = u64min(g[s >> 3], k);
    }
    unsigned long long lane_key = u64min(u64min(g[0], g[1]), u64min(g[2], g[3]));

    int   wonJ = 0;
    float wonV = 0.0f;
    const float INF = __uint_as_float(0x7f800000u);

    for (int n = 0; n < Kc; ++n) {
        unsigned long long w = lane_key;
        #pragma unroll
        for (int off = 32; off; off >>= 1) {
            const unsigned long long o =
                (unsigned long long)__shfl_xor((long long)w, off, 64);
            w = u64min(w, o);
        }
        const int j = (int)(w & 0xffffffffULL);   // uniform winner
        if (lane == n) {
            wonJ = j;
            wonV = __uint_as_float((unsigned)(w >> 32));
        }
        // owner lane invalidates + rebuilds its group
        if ((j & 63) == lane) {
            const int sw = j >> 6;                // 0..31
            sval[wv][sw][lane] = INF;
            const int gi = sw >> 3;
            const float* bp = &sval[wv][gi * 8][lane];
            const unsigned jb = (unsigned)((gi << 9) | lane);
            unsigned long long m = ~0ULL;
            #pragma unroll
            for (int ss = 0; ss < 8; ++ss) {
                const float v = bp[ss * 64];
                const unsigned long long k =
                    ((unsigned long long)__float_as_uint(v) << 32) | (jb + (ss << 6));
                m = u64min(m, k);
            }
            #pragma unroll
            for (int gi2 = 0; gi2 < 4; ++gi2) if (gi2 == gi) g[gi2] = m;
            lane_key = u64min(u64min(g[0], g[1]), u64min(g[2], g[3]));
        }
    }

    if (lane < Kc) {
        eidx[row * Kc + lane] = wonJ;
        dnb[row * Kc + lane] = wonV;
        outEidx[(size_t)row * Kc + lane] = (float)wonJ;
    }
}

// ---------------- Kernel 2: features + MFMA GEMM + LayerNorm ----------------
// block = 4 residues (120 edges, M padded to 128), N=128, K=416 chunked by 32
__global__ __launch_bounds__(256) void edge_mfma(
    const float* __restrict__ X, const int* __restrict__ ridx, const int* __restrict__ clab,
    const float* __restrict__ pe_w, const float* __restrict__ pe_b,
    const unsigned short* __restrict__ Wt,   // bf16 [128][416] (n-major)
    const float* __restrict__ ln_g, const float* __restrict__ ln_b,
    const int* __restrict__ eidx, const float* __restrict__ dnb,
    float* __restrict__ outE)
{
    __shared__ unsigned short A[128][40];    // feature chunk, bf16, row pad 40
    __shared__ unsigned short Bs[128][40];   // Wt chunk [n][k], bf16, row pad 40
    __shared__ float atomsA[4][16];          // residue atoms (N,C,Ca,Cb,O)*3
    __shared__ float atomsB[120][16];        // neighbor atoms
    __shared__ float dnb_s[120];
    __shared__ int   pidx[120];              // positional embedding row

    const int blk = blockIdx.x;              // 2048
    const int t   = threadIdx.x;
    const int lane = t & 63, w = t >> 6;
    const int b   = blk >> 9;                // batch (512 blocks per batch)

    // --- staging: atoms + Cb for 4 residues and their 120 neighbors ---
    if (t < 124) {
        int j, rowi = 0;
        float* dst;
        if (t < 120) {
            const int r = t / 30;
            rowi = blk * 4 + r;              // global residue row (b*L + i)
            j = eidx[rowi * Kc + (t - r * 30)];
            dst = &atomsB[t][0];
            dnb_s[t] = dnb[rowi * Kc + (t - r * 30)];
            const int off = ridx[rowi] - ridx[b * Lc + j];
            const int ec  = (clab[rowi] == clab[b * Lc + j]) ? 1 : 0;
            pidx[t] = ec ? min(max(off + 32, 0), 64) : 65;
        } else {
            j = (blk * 4 + (t - 120)) & (Lc - 1);
            dst = &atomsA[t - 120][0];
        }
        const float* p = X + (size_t)(b * Lc + j) * 12;
        const float Nx = p[0],  Ny = p[1],  Nz = p[2];
        const float Cx = p[3],  Cy = p[4],  Cz = p[5];
        const float Cax = p[6], Cay = p[7], Caz = p[8];
        const float Ox = p[9],  Oy = p[10], Oz = p[11];
        const float bx = Cax - Nx, by = Cay - Ny, bz = Caz - Nz;
        const float cx = Cx - Cax, cy = Cy - Cay, cz = Cz - Caz;
        const float ax = by * cz - bz * cy;
        const float ay = bz * cx - bx * cz;
        const float az = bx * cy - by * cx;
        dst[0] = Nx;  dst[1] = Ny;  dst[2] = Nz;
        dst[3] = Cx;  dst[4] = Cy;  dst[5] = Cz;
        dst[6] = Cax; dst[7] = Cay; dst[8] = Caz;
        dst[9]  = -0.58273431f * ax + 0.56802827f * bx - 0.54067466f * cx + Cax;
        dst[10] = -0.58273431f * ay + 0.56802827f * by - 0.54067466f * cy + Cay;
        dst[11] = -0.58273431f * az + 0.56802827f * bz - 0.54067466f * cz + Caz;
        dst[12] = Ox; dst[13] = Oy; dst[14] = Oz;
    }

    f32x4 acc[2][8];
    #pragma unroll
    for (int m = 0; m < 2; ++m)
        #pragma unroll
        for (int n = 0; n < 8; ++n) acc[m][n] = (f32x4){0.f, 0.f, 0.f, 0.f};

    const int kg = (lane >> 4) * 8;          // k-group offset within chunk
    const int cl = lane & 15;

    for (int kc = 0; kc < 13; ++kc) {
        __syncthreads();                     // staging done / prev MFMA reads done

        // load Wt chunk -> Bs (2x 16B per thread, coalesced 64B per n-row)
        {
            #pragma unroll
            for (int u = 0; u < 2; ++u) {
                const int id = u * 256 + t;  // 0..511
                const int n = id >> 2, g = id & 3;
                *(ushortx8*)&Bs[n][g * 8] =
                    *(const ushortx8*)&Wt[n * Fc + kc * 32 + g * 8];
            }
        }

        // compute feature chunk -> A
        if (t < 240) {
            const int e = t >> 1, h = t & 1;
            unsigned short v[16];
            if (kc == 0) {
                if (h == 0) {
                    const float* pr = pe_w + pidx[e] * 16;
                    #pragma unroll
                    for (int m = 0; m < 16; ++m) v[m] = f2bf(pr[m] + pe_b[m]);
                } else {
                    const float d = dnb_s[e];
                    #pragma unroll
                    for (int m = 0; m < 16; ++m) {
                        const float u = (d - (2.0f + (4.0f / 3.0f) * m)) * 0.8f;
                        v[m] = f2bf(__expf(-u * u));
                    }
                }
            } else {
                const int p = 2 * kc - 2 + h;
                const int a_ = c_pa[p], b_ = c_pb[p];
                const float* Ai = &atomsA[e / 30][0];
                const float* Bj = &atomsB[e][0];
                const float dx = Ai[a_ * 3 + 0] - Bj[b_ * 3 + 0];
                const float dy = Ai[a_ * 3 + 1] - Bj[b_ * 3 + 1];
                const float dz = Ai[a_ * 3 + 2] - Bj[b_ * 3 + 2];
                const float d = sqrtf(dx * dx + dy * dy + dz * dz + 1e-6f);
                #pragma unroll
                for (int m = 0; m < 16; ++m) {
                    const float u = (d - (2.0f + (4.0f / 3.0f) * m)) * 0.8f;
                    v[m] = f2bf(__expf(-u * u));
                }
            }
            ushortx8 lo, hi;
            #pragma unroll
            for (int m = 0; m < 8; ++m) { lo[m] = v[m]; hi[m] = v[m + 8]; }
            *(ushortx8*)&A[e][h * 16]     = lo;
            *(ushortx8*)&A[e][h * 16 + 8] = hi;
        }

        __syncthreads();

        // MFMA: wave w owns rows w*32..w*32+31, all 128 cols
        bf16x8 af0 = __builtin_bit_cast(bf16x8, *(const ushortx8*)&A[w * 32 + cl][kg]);
        bf16x8 af1 = __builtin_bit_cast(bf16x8, *(const ushortx8*)&A[w * 32 + 16 + cl][kg]);
        #pragma unroll
        for (int n = 0; n < 8; ++n) {
            bf16x8 bf = __builtin_bit_cast(bf16x8, *(const ushortx8*)&Bs[n * 16 + cl][kg]);
            acc[0][n] = __builtin_amdgcn_mfma_f32_16x16x32_bf16(af0, bf, acc[0][n], 0, 0, 0);
            acc[1][n] = __builtin_amdgcn_mfma_f32_16x16x32_bf16(af1, bf, acc[1][n], 0, 0, 0);
        }
    }

    // --- LayerNorm + store ---
    float gcol[8], bcol[8];
    #pragma unroll
    for (int n = 0; n < 8; ++n) {
        gcol[n] = ln_g[n * 16 + cl];
        bcol[n] = ln_b[n * 16 + cl];
    }
    #pragma unroll
    for (int m = 0; m < 2; ++m) {
        #pragma unroll
        for (int reg = 0; reg < 4; ++reg) {
            const int rl = w * 32 + m * 16 + (lane >> 4) * 4 + reg;
            float s1 = 0.f, s2 = 0.f;
            #pragma unroll
            for (int n = 0; n < 8; ++n) {
                const float v = acc[m][n][reg];
                s1 += v; s2 += v * v;
            }
            #pragma unroll
            for (int off = 1; off < 16; off <<= 1) {
                s1 += __shfl_xor(s1, off, 64);
                s2 += __shfl_xor(s2, off, 64);
            }
            if (rl < 120) {
                const float mu = s1 * (1.0f / 128.0f);
                const float var = s2 * (1.0f / 128.0f) - mu * mu;
                const float rstd = rsqrtf(var + 1e-5f);
                const size_t base = ((size_t)(blk * 120 + rl)) * 128 + cl;
                #pragma unroll
                for (int n = 0; n < 8; ++n) {
                    outE[base + n * 16] =
                        (acc[m][n][reg] - mu) * rstd * gcol[n] + bcol[n];
                }
            }
        }
    }
}

extern "C" void kernel_launch(void* const* d_in, const int* in_sizes, int n_in,
                              void* d_out, int out_size, void* d_ws, size_t ws_size,
                              hipStream_t stream) {
    const float* X     = (const float*)d_in[0];
    const float* mask  = (const float*)d_in[1];
    const int*   ridx  = (const int*)d_in[2];
    const int*   clab  = (const int*)d_in[3];
    const float* pe_w  = (const float*)d_in[4];
    const float* pe_b  = (const float*)d_in[5];
    const float* edge_w = (const float*)d_in[6];
    const float* ln_g  = (const float*)d_in[7];
    const float* ln_b  = (const float*)d_in[8];

    float* outE   = (float*)d_out;
    float* outIdx = outE + (size_t)Bc * Lc * Kc * Nc;   // E_idx region (as float)

    int*   eidx = (int*)d_ws;
    float* dnbw = (float*)((char*)d_ws + (size_t)Bc * Lc * Kc * sizeof(int));
    unsigned short* Wt = (unsigned short*)((char*)d_ws + (size_t)2 * Bc * Lc * Kc * sizeof(int));

    prep_w<<<(Fc * Nc + 255) / 256, 256, 0, stream>>>(edge_w, Wt);
    topk_lds<<<Bc * Lc / 4, 256, 0, stream>>>(X, mask, eidx, dnbw, outIdx);
    edge_mfma<<<Bc * Lc / 4, 256, 0, stream>>>(X, ridx, clab, pe_w, pe_b, Wt,
                                               ln_g, ln_b, eidx, dnbw, outE);
}

// Round 5
// 136.442 us; speedup vs baseline: 7.8256x; 1.0530x over previous
//
#include <hip/hip_runtime.h>
#include <hip/hip_bf16.h>
#include <cstdint>
#include <cstddef>

#define Bc 4
#define Lc 2048
#define Kc 30
#define Fc 416
#define Nc 128

typedef __bf16 bf16x8 __attribute__((ext_vector_type(8)));
typedef float  f32x4  __attribute__((ext_vector_type(4)));
typedef unsigned short ushortx8 __attribute__((ext_vector_type(8)));

// atom index map: N=0, C=1, Ca=2, Cb=3, O=4
__constant__ int c_pa[24] = {0,2,3,1,1,1,0,0,3,0,2,3,2,3,2,4,1,4,0,4,3,4,4,2};
__constant__ int c_pb[24] = {0,2,3,0,2,3,2,3,2,1,1,1,0,0,3,4,4,1,4,0,4,2,3,2};

__device__ __forceinline__ unsigned long long u64min(unsigned long long a, unsigned long long b) {
    return a < b ? a : b;
}

__device__ __forceinline__ unsigned short f2bf(float f) {
    __hip_bfloat16 h = __float2bfloat16(f);
    return *(unsigned short*)&h;
}

// ---------------- Kernel 0: W -> bf16, transposed Wt[n][k] ----------------
__global__ __launch_bounds__(256) void prep_w(const float* __restrict__ Wg,
                                              unsigned short* __restrict__ Wt) {
    const int id = blockIdx.x * 256 + threadIdx.x;   // 416*128 = 53248
    if (id < Fc * Nc) {
        const int n = id / Fc, k = id - n * Fc;
        Wt[id] = f2bf(Wg[k * Nc + n]);
    }
}

// ---------------- Kernel 1: top-k, one wave per row, pool in LDS ----------------
__global__ __launch_bounds__(256) void topk_lds(
    const float* __restrict__ X, const float* __restrict__ mask,
    int* __restrict__ eidx, float* __restrict__ dnb, float* __restrict__ outEidx)
{
#pragma clang fp contract(off)
    __shared__ float sval[4][32][64];          // [wave][s][lane], 32 KB
    const int t = threadIdx.x;
    const int lane = t & 63, wv = t >> 6;
    const int row = blockIdx.x * 4 + wv;       // b*L + i
    const int b   = row >> 11;
    const int i   = row & (Lc - 1);

    const float* Xb = X + (size_t)(b * Lc) * 12;
    const float cix = Xb[(size_t)i * 12 + 3];
    const float ciy = Xb[(size_t)i * 12 + 4];
    const float ciz = Xb[(size_t)i * 12 + 5];
    const float mi  = mask[row];

    // pass 1: D -> LDS, wave max
    float dmax = -1e30f;
    #pragma unroll 8
    for (int s = 0; s < 32; ++s) {
        const int j = s * 64 + lane;
        const float dx = Xb[(size_t)j * 12 + 3] - cix;
        const float dy = Xb[(size_t)j * 12 + 4] - ciy;
        const float dz = Xb[(size_t)j * 12 + 5] - ciz;
        const float ss = dx * dx + dy * dy + dz * dz;
        const float dist = sqrtf(ss + 1e-6f);
        const float D = (mi * mask[b * Lc + j]) * dist;
        sval[wv][s][lane] = D;
        dmax = fmaxf(dmax, D);
    }
    #pragma unroll
    for (int off = 32; off; off >>= 1) dmax = fmaxf(dmax, __shfl_xor(dmax, off, 64));

    // pass 2: Dadj -> LDS, build group argmins (u64 = valbits<<32 | j)
    unsigned long long g[4] = {~0ULL, ~0ULL, ~0ULL, ~0ULL};
    #pragma unroll 8
    for (int s = 0; s < 32; ++s) {
        const int j = s * 64 + lane;
        const float m2 = mi * mask[b * Lc + j];
        const float Dadj = sval[wv][s][lane] + (1.0f - m2) * dmax;
        sval[wv][s][lane] = Dadj;
        const unsigned long long k =
            ((unsigned long long)__float_as_uint(Dadj) << 32) | (unsigned)j;
        g[s >> 3] = u64min(g[s >> 3], k);
    }
    unsigned long long lane_key = u64min(u64min(g[0], g[1]), u64min(g[2], g[3]));

    int   wonJ = 0;
    float wonV = 0.0f;
    const float INF = __uint_as_float(0x7f800000u);

    for (int n = 0; n < Kc; ++n) {
        unsigned long long w = lane_key;
        #pragma unroll
        for (int off = 32; off; off >>= 1) {
            const unsigned long long o =
                (unsigned long long)__shfl_xor((long long)w, off, 64);
            w = u64min(w, o);
        }
        const int j = (int)(w & 0xffffffffULL);   // uniform winner
        if (lane == n) {
            wonJ = j;
            wonV = __uint_as_float((unsigned)(w >> 32));
        }
        // owner lane invalidates + rebuilds its group
        if ((j & 63) == lane) {
            const int sw = j >> 6;                // 0..31
            sval[wv][sw][lane] = INF;
            const int gi = sw >> 3;
            const float* bp = &sval[wv][gi * 8][lane];
            const unsigned jb = (unsigned)((gi << 9) | lane);
            unsigned long long m = ~0ULL;
            #pragma unroll
            for (int ss = 0; ss < 8; ++ss) {
                const float v = bp[ss * 64];
                const unsigned long long k =
                    ((unsigned long long)__float_as_uint(v) << 32) | (jb + (ss << 6));
                m = u64min(m, k);
            }
            #pragma unroll
            for (int gi2 = 0; gi2 < 4; ++gi2) if (gi2 == gi) g[gi2] = m;
            lane_key = u64min(u64min(g[0], g[1]), u64min(g[2], g[3]));
        }
    }

    if (lane < Kc) {
        eidx[row * Kc + lane] = wonJ;
        dnb[row * Kc + lane] = wonV;
        outEidx[(size_t)row * Kc + lane] = (float)wonJ;
    }
}

// ---------------- Kernel 2: reg-A MFMA GEMM + LayerNorm ----------------
// block = 4 residues (120 edges, M padded to 128), N=128, K=416 chunked by 32.
// A-fragments computed per-lane in registers (no LDS A-tile).
// B double-buffered in fragment-linear LDS layout (conflict-free).
__global__ __launch_bounds__(256) void edge_mfma2(
    const float* __restrict__ X, const int* __restrict__ ridx, const int* __restrict__ clab,
    const float* __restrict__ pe_w, const float* __restrict__ pe_b,
    const unsigned short* __restrict__ Wt,   // bf16 [128][416] (n-major)
    const float* __restrict__ ln_g, const float* __restrict__ ln_b,
    const int* __restrict__ eidx, const float* __restrict__ dnb,
    float* __restrict__ outE)
{
    __shared__ unsigned short Bs[2][8][512]; // [buf][n-tile][lane*8] fragment-linear
    __shared__ float atomsA[4][17];          // residue atoms, padded (bank-safe)
    __shared__ float atomsB[120][17];        // neighbor atoms, padded
    __shared__ float dnb_s[120];
    __shared__ int   pid_s[120];

    const int blk = blockIdx.x;              // 2048
    const int t   = threadIdx.x;
    const int lane = t & 63, w = t >> 6;
    const int b   = blk >> 9;
    const int cl  = lane & 15, q = lane >> 4;

    // --- staging: atoms + Cb for 4 residues and their 120 neighbors ---
    if (t < 124) {
        int j, rowi = 0;
        float* dst;
        if (t < 120) {
            const int r = t / 30;
            rowi = blk * 4 + r;
            j = eidx[rowi * Kc + (t - r * 30)];
            dst = &atomsB[t][0];
            dnb_s[t] = dnb[rowi * Kc + (t - r * 30)];
            const int off = ridx[rowi] - ridx[b * Lc + j];
            const int ec  = (clab[rowi] == clab[b * Lc + j]) ? 1 : 0;
            pid_s[t] = ec ? min(max(off + 32, 0), 64) : 65;
        } else {
            j = (blk * 4 + (t - 120)) & (Lc - 1);
            dst = &atomsA[t - 120][0];
        }
        const float* p = X + (size_t)(b * Lc + j) * 12;
        const float Nx = p[0],  Ny = p[1],  Nz = p[2];
        const float Cx = p[3],  Cy = p[4],  Cz = p[5];
        const float Cax = p[6], Cay = p[7], Caz = p[8];
        const float Ox = p[9],  Oy = p[10], Oz = p[11];
        const float bx = Cax - Nx, by = Cay - Ny, bz = Caz - Nz;
        const float cx = Cx - Cax, cy = Cy - Cay, cz = Cz - Caz;
        const float ax = by * cz - bz * cy;
        const float ay = bz * cx - bx * cz;
        const float az = bx * cy - by * cx;
        dst[0] = Nx;  dst[1] = Ny;  dst[2] = Nz;
        dst[3] = Cx;  dst[4] = Cy;  dst[5] = Cz;
        dst[6] = Cax; dst[7] = Cay; dst[8] = Caz;
        dst[9]  = -0.58273431f * ax + 0.56802827f * bx - 0.54067466f * cx + Cax;
        dst[10] = -0.58273431f * ay + 0.56802827f * by - 0.54067466f * cy + Cay;
        dst[11] = -0.58273431f * az + 0.56802827f * bz - 0.54067466f * cz + Caz;
        dst[12] = Ox; dst[13] = Oy; dst[14] = Oz;
    }

    // --- Wt staging geometry (fragment-linear): thread t covers n={w, w+4} ---
    const int wrow0 = w * 16 + cl;           // n = w
    const int wrow1 = (w + 4) * 16 + cl;     // n = w+4
    const int wcol  = q * 8;
    const unsigned short* gW0 = Wt + wrow0 * Fc + wcol;
    const unsigned short* gW1 = Wt + wrow1 * Fc + wcol;

    // prologue: stage chunk 0
    {
        ushortx8 p0 = *(const ushortx8*)gW0;
        ushortx8 p1 = *(const ushortx8*)gW1;
        *(ushortx8*)&Bs[0][w][lane * 8]     = p0;
        *(ushortx8*)&Bs[0][w + 4][lane * 8] = p1;
    }
    __syncthreads();

    f32x4 acc[2][8];
    #pragma unroll
    for (int m = 0; m < 2; ++m)
        #pragma unroll
        for (int n = 0; n < 8; ++n) acc[m][n] = (f32x4){0.f, 0.f, 0.f, 0.f};

    const int row0 = w * 32 + cl;
    const int row1 = row0 + 16;
    const int e0 = min(row0, 119), e1 = min(row1, 119);
    const int r0 = e0 / 30,        r1 = e1 / 30;

    // per-lane A-fragment: 8 feature values for (edge e, k-slice q*8 of chunk kc)
    auto afrag = [&](int kc, int e, int r) -> bf16x8 {
        float v[8];
        if (kc == 0) {
            if (q < 2) {
                const int base = pid_s[e] * 16 + q * 8;
                const float4 p0 = *(const float4*)&pe_w[base];
                const float4 p1 = *(const float4*)&pe_w[base + 4];
                const float4 b0 = *(const float4*)&pe_b[q * 8];
                const float4 b1 = *(const float4*)&pe_b[q * 8 + 4];
                v[0] = p0.x + b0.x; v[1] = p0.y + b0.y;
                v[2] = p0.z + b0.z; v[3] = p0.w + b0.w;
                v[4] = p1.x + b1.x; v[5] = p1.y + b1.y;
                v[6] = p1.z + b1.z; v[7] = p1.w + b1.w;
            } else {
                const float d = dnb_s[e];
                const int m0 = (q - 2) * 8;
                #pragma unroll
                for (int m = 0; m < 8; ++m) {
                    const float u = (d - (2.0f + (4.0f / 3.0f) * (m0 + m))) * 0.8f;
                    v[m] = __expf(-u * u);
                }
            }
        } else {
            const int p  = 2 * kc - 2 + (q >> 1);
            const int a_ = c_pa[p], b_ = c_pb[p];
            const float dx = atomsA[r][a_ * 3 + 0] - atomsB[e][b_ * 3 + 0];
            const float dy = atomsA[r][a_ * 3 + 1] - atomsB[e][b_ * 3 + 1];
            const float dz = atomsA[r][a_ * 3 + 2] - atomsB[e][b_ * 3 + 2];
            const float d = sqrtf(dx * dx + dy * dy + dz * dz + 1e-6f);
            const int m0 = (q & 1) * 8;
            #pragma unroll
            for (int m = 0; m < 8; ++m) {
                const float u = (d - (2.0f + (4.0f / 3.0f) * (m0 + m))) * 0.8f;
                v[m] = __expf(-u * u);
            }
        }
        ushortx8 o;
        #pragma unroll
        for (int m = 0; m < 8; ++m) o[m] = f2bf(v[m]);
        return __builtin_bit_cast(bf16x8, o);
    };

    for (int kc = 0; kc < 13; ++kc) {
        const int cur = kc & 1;
        ushortx8 st0, st1;
        if (kc < 12) {                        // issue next chunk's loads early
            st0 = *(const ushortx8*)(gW0 + (kc + 1) * 32);
            st1 = *(const ushortx8*)(gW1 + (kc + 1) * 32);
        }
        const bf16x8 a0 = afrag(kc, e0, r0);
        const bf16x8 a1 = afrag(kc, e1, r1);
        #pragma unroll
        for (int n = 0; n < 8; ++n) {
            bf16x8 bf = __builtin_bit_cast(bf16x8,
                *(const ushortx8*)&Bs[cur][n][lane * 8]);
            acc[0][n] = __builtin_amdgcn_mfma_f32_16x16x32_bf16(a0, bf, acc[0][n], 0, 0, 0);
            acc[1][n] = __builtin_amdgcn_mfma_f32_16x16x32_bf16(a1, bf, acc[1][n], 0, 0, 0);
        }
        if (kc < 12) {                        // write-late (T14)
            *(ushortx8*)&Bs[cur ^ 1][w][lane * 8]     = st0;
            *(ushortx8*)&Bs[cur ^ 1][w + 4][lane * 8] = st1;
        }
        __syncthreads();
    }

    // --- LayerNorm + store ---
    float gcol[8], bcol[8];
    #pragma unroll
    for (int n = 0; n < 8; ++n) {
        gcol[n] = ln_g[n * 16 + cl];
        bcol[n] = ln_b[n * 16 + cl];
    }
    #pragma unroll
    for (int m = 0; m < 2; ++m) {
        #pragma unroll
        for (int reg = 0; reg < 4; ++reg) {
            const int rl = w * 32 + m * 16 + q * 4 + reg;
            float s1 = 0.f, s2 = 0.f;
            #pragma unroll
            for (int n = 0; n < 8; ++n) {
                const float v = acc[m][n][reg];
                s1 += v; s2 += v * v;
            }
            #pragma unroll
            for (int off = 1; off < 16; off <<= 1) {
                s1 += __shfl_xor(s1, off, 64);
                s2 += __shfl_xor(s2, off, 64);
            }
            if (rl < 120) {
                const float mu = s1 * (1.0f / 128.0f);
                const float var = s2 * (1.0f / 128.0f) - mu * mu;
                const float rstd = rsqrtf(var + 1e-5f);
                const size_t base = ((size_t)(blk * 120 + rl)) * 128 + cl;
                #pragma unroll
                for (int n = 0; n < 8; ++n) {
                    outE[base + n * 16] =
                        (acc[m][n][reg] - mu) * rstd * gcol[n] + bcol[n];
                }
            }
        }
    }
}

extern "C" void kernel_launch(void* const* d_in, const int* in_sizes, int n_in,
                              void* d_out, int out_size, void* d_ws, size_t ws_size,
                              hipStream_t stream) {
    const float* X     = (const float*)d_in[0];
    const float* mask  = (const float*)d_in[1];
    const int*   ridx  = (const int*)d_in[2];
    const int*   clab  = (const int*)d_in[3];
    const float* pe_w  = (const float*)d_in[4];
    const float* pe_b  = (const float*)d_in[5];
    const float* edge_w = (const float*)d_in[6];
    const float* ln_g  = (const float*)d_in[7];
    const float* ln_b  = (const float*)d_in[8];

    float* outE   = (float*)d_out;
    float* outIdx = outE + (size_t)Bc * Lc * Kc * Nc;   // E_idx region (as float)

    int*   eidx = (int*)d_ws;
    float* dnbw = (float*)((char*)d_ws + (size_t)Bc * Lc * Kc * sizeof(int));
    unsigned short* Wt = (unsigned short*)((char*)d_ws + (size_t)2 * Bc * Lc * Kc * sizeof(int));

    prep_w<<<(Fc * Nc + 255) / 256, 256, 0, stream>>>(edge_w, Wt);
    topk_lds<<<Bc * Lc / 4, 256, 0, stream>>>(X, mask, eidx, dnbw, outIdx);
    edge_mfma2<<<Bc * Lc / 4, 256, 0, stream>>>(X, ridx, clab, pe_w, pe_b, Wt,
                                                ln_g, ln_b, eidx, dnbw, outE);
}